// Round 1
// baseline (405.180 us; speedup 1.0000x reference)
//
#include <hip/hip_runtime.h>

// Problem constants (match reference).
#define BB 4
#define CC 64
#define HH 512
#define WW 512
#define PP 409600

// Phase 1: last-write-wins winner selection. Highest pillar index wins,
// which matches sequential assignment order (later writes overwrite earlier).
__global__ void pillar_winner_kernel(const int4* __restrict__ coords,
                                     int* __restrict__ winner) {
    int p = blockIdx.x * blockDim.x + threadIdx.x;
    if (p >= PP) return;
    int4 c = coords[p];          // [b, z, y, x]
    int b = c.x, y = c.z, x = c.w;
    if ((unsigned)y < (unsigned)HH && (unsigned)x < (unsigned)WW &&
        (unsigned)b < (unsigned)BB) {
        int flat = (b * HH + y) * WW + x;
        atomicMax(&winner[flat], p);
    }
}

// Phase 2: each thread owns 4 consecutive x positions of one (b, y) row.
// Reads 4 winner ids (int4, coalesced), gathers feature rows as float4,
// transposes in registers, writes float4 along x for each of 64 channels.
// Cells with no winner get zeros, so the whole canvas is covered.
__global__ void canvas_write_kernel(const float* __restrict__ feat,
                                    const int* __restrict__ winner,
                                    float* __restrict__ out) {
    int idx = blockIdx.x * blockDim.x + threadIdx.x;   // over B*H*W/4
    int x4   = idx & (WW / 4 - 1);       // 0..127
    int rest = idx >> 7;                 // / (W/4)
    int y    = rest & (HH - 1);          // 0..511
    int b    = rest >> 9;                // 0..3

    int cell = (b * HH + y) * WW + x4 * 4;
    int4 w = *(const int4*)(winner + cell);

    const float4 zero = make_float4(0.f, 0.f, 0.f, 0.f);
    const float4* fq = (const float4*)feat;   // feat rows: CC/4 float4 each

    // Output base for channel 0 at this (b, y, x4*4); channel stride = H*W.
    int obase = ((b * CC) * HH + y) * WW + x4 * 4;

#pragma unroll
    for (int c4 = 0; c4 < CC / 4; ++c4) {
        float4 a = (w.x >= 0) ? fq[w.x * (CC / 4) + c4] : zero;
        float4 bq = (w.y >= 0) ? fq[w.y * (CC / 4) + c4] : zero;
        float4 cq = (w.z >= 0) ? fq[w.z * (CC / 4) + c4] : zero;
        float4 dq = (w.w >= 0) ? fq[w.w * (CC / 4) + c4] : zero;

        // Transpose: channel c4*4+j takes component j of each winner row.
        float4 o0 = make_float4(a.x, bq.x, cq.x, dq.x);
        float4 o1 = make_float4(a.y, bq.y, cq.y, dq.y);
        float4 o2 = make_float4(a.z, bq.z, cq.z, dq.z);
        float4 o3 = make_float4(a.w, bq.w, cq.w, dq.w);

        int base = obase + (c4 * 4) * (HH * WW);
        *(float4*)(out + base)                = o0;
        *(float4*)(out + base + 1 * HH * WW)  = o1;
        *(float4*)(out + base + 2 * HH * WW)  = o2;
        *(float4*)(out + base + 3 * HH * WW)  = o3;
    }
}

extern "C" void kernel_launch(void* const* d_in, const int* in_sizes, int n_in,
                              void* d_out, int out_size, void* d_ws, size_t ws_size,
                              hipStream_t stream) {
    const float* feat  = (const float*)d_in[0];   // [P, C] fp32
    const int4* coords = (const int4*)d_in[1];    // [P, 4] int32
    float* out         = (float*)d_out;           // [B, C, H, W] fp32
    int* winner        = (int*)d_ws;              // [B*H*W] int32 (4 MiB)

    // winner = -1 everywhere (0xFF bytes).
    hipMemsetAsync(winner, 0xFF, (size_t)BB * HH * WW * sizeof(int), stream);

    // Phase 1: winner selection.
    {
        int threads = 256;
        int blocks = (PP + threads - 1) / threads;
        pillar_winner_kernel<<<blocks, threads, 0, stream>>>(coords, winner);
    }

    // Phase 2: write the full canvas.
    {
        int threads = 256;
        int total = BB * HH * WW / 4;             // 262144 threads
        int blocks = total / threads;             // 1024 blocks
        canvas_write_kernel<<<blocks, threads, 0, stream>>>(feat, winner, out);
    }
}